// Round 12
// baseline (218.597 us; speedup 1.0000x reference)
//
#include <hip/hip_runtime.h>
#include <hip/hip_bf16.h>

typedef __attribute__((ext_vector_type(4))) float  float4v;
typedef __attribute__((ext_vector_type(4))) float  f32x4;
typedef __attribute__((ext_vector_type(8))) short  bf16x8;
typedef __attribute__((ext_vector_type(4))) short  bf16x4;

#define LDK     40      // 32 k + 8 pad (shorts); 80 B row stride -> 20-bank stride, 2-way max
#define XSTR_B  65536   // 32*32*64
#define XSTR_H  2048    // 32*64
#define XSTR_W  64
#define WSTR_P  36864   // 576*64
#define OSTR_B  57600   // 30*30*64

__device__ __forceinline__ short f2bf(float f) {
  union { float f; unsigned u; } v; v.f = f;
  unsigned r = v.u + 0x7fffu + ((v.u >> 16) & 1u);  // RNE
  return (short)(r >> 16);
}
__device__ __forceinline__ bf16x4 cvt4(float4v v) {
  bf16x4 o; o[0] = f2bf(v.x); o[1] = f2bf(v.y); o[2] = f2bf(v.z); o[3] = f2bf(v.w);
  return o;
}

// Wave-private design: each wave owns a 64(batch) x 16(filter) output slice with
// its OWN LDS staging buffers. No inter-wave data sharing -> ZERO barriers.
// Same-wave DS ops are processed in order, so write->read needs no __syncthreads.
__global__ __launch_bounds__(256, 2)
void lc2d_kernel(const float* __restrict__ x, const float* __restrict__ wgt,
                 const float* __restrict__ bias, float* __restrict__ out) {
  __shared__ short Xs[4 * 2 * 64 * LDK];   // 4 waves x 2 bufs x [64 b][LDK k]  (40960 B)
  __shared__ short Ws[4 * 2 * 16 * LDK];   // 4 waves x 2 bufs x [16 o][LDK k]  (10240 B)

  // bijective XCD swizzle: nwg=900, 8 XCDs, q=112, rr=4
  int orig = blockIdx.x;
  int xcd  = orig & 7;
  int idx  = orig >> 3;
  int p = (xcd < 4 ? xcd * 113 : 452 + (xcd - 4) * 112) + idx;
  int r = p / 30;
  int c = p - r * 30;

  int tid  = threadIdx.x;
  int lane = tid & 63;
  int wid  = tid >> 6;     // wave id = filter-slice id (o in [wid*16, wid*16+16))
  int l16  = lane & 15;
  int lhi  = lane >> 4;

  // x staging coords: rep i covers batch rows i*8..i*8+7; 8 lanes x 16B = one 128B row-half
  int bx  = lane >> 3;          // 0..7
  int kx0 = (lane & 7) * 4;     // k-offset within 32-chunk
  // W staging coords: rep i covers k-rows i*16..i*16+15; 4 lanes x 16B = wave's 64B row-slice
  int krs = lane >> 2;          // 0..15
  int wo0 = (lane & 3) * 4;     // o-offset within 16-slice

  short* Xw = Xs + wid * (2 * 64 * LDK);
  short* Ww = Ws + wid * (2 * 16 * LDK);

  const float* xbase = x + r * XSTR_H + c * XSTR_W + kx0;
  const float* wbase = wgt + p * WSTR_P + wid * 16 + wo0;

  // depth-2 ping-pong register prefetch (indices compile-time after full unroll)
  float4v xv[2][8];
  float4v wv[2][2];
  f32x4 acc[4] = {{0.f,0.f,0.f,0.f},{0.f,0.f,0.f,0.f},{0.f,0.f,0.f,0.f},{0.f,0.f,0.f,0.f}};

  const float bval = bias[(r * 30 + c) * 64 + wid * 16 + l16];

  // chunk t: tap = t/2 (di,dj), channel-half = (t&1)*32; covers k = t*32..t*32+31
  auto issue = [&](int t, int pb) {
    int tap = t >> 1, di = tap / 3, dj = tap - di * 3;
    const float* xa = xbase + di * XSTR_H + dj * XSTR_W + (t & 1) * 32;
#pragma unroll
    for (int i = 0; i < 8; ++i)
      xv[pb][i] = *(const float4v*)(xa + (long)(i * 8 + bx) * XSTR_B);
    const float* wa = wbase + t * 32 * 64;
#pragma unroll
    for (int i = 0; i < 2; ++i)
      wv[pb][i] = *(const float4v*)(wa + (i * 16 + krs) * 64);
  };

  issue(0, 0);
  issue(1, 1);

#pragma unroll
  for (int t = 0; t < 18; ++t) {
    const int pb = t & 1;
    short* Xb = Xw + pb * (64 * LDK);
    short* Wb = Ww + pb * (16 * LDK);
    // ---- stage x: 8 x bf16x4 (b64) writes, wave-private
#pragma unroll
    for (int i = 0; i < 8; ++i)
      *(bf16x4*)&Xb[(i * 8 + bx) * LDK + kx0] = cvt4(xv[pb][i]);
    // ---- stage W transposed: lane holds W[k=kr][o=wo0..wo0+3] -> Wb[o][k]
#pragma unroll
    for (int i = 0; i < 2; ++i) {
      int kr = i * 16 + krs;
      Wb[(wo0 + 0) * LDK + kr] = f2bf(wv[pb][i].x);
      Wb[(wo0 + 1) * LDK + kr] = f2bf(wv[pb][i].y);
      Wb[(wo0 + 2) * LDK + kr] = f2bf(wv[pb][i].z);
      Wb[(wo0 + 3) * LDK + kr] = f2bf(wv[pb][i].w);
    }
    if (t < 16) issue(t + 2, pb);   // refill consumed bank; no barrier ever drains it
    // ---- frags + 4 MFMA (same-wave DS in-order: reads see the writes above)
    bf16x8 bf = *(const bf16x8*)&Wb[l16 * LDK + lhi * 8];
#pragma unroll
    for (int m = 0; m < 4; ++m) {
      bf16x8 af = *(const bf16x8*)&Xb[(m * 16 + l16) * LDK + lhi * 8];
      acc[m] = __builtin_amdgcn_mfma_f32_16x16x32_bf16(af, bf, acc[m], 0, 0, 0);
    }
  }

  // ---- epilogue: bias + relu (D layout: col = lane&15 -> o, row = lhi*4 + j -> batch)
  float* ob = out + (r * 30 + c) * 64 + wid * 16 + l16;
#pragma unroll
  for (int m = 0; m < 4; ++m)
#pragma unroll
    for (int j = 0; j < 4; ++j) {
      int b = m * 16 + lhi * 4 + j;
      ob[(long)b * OSTR_B] = fmaxf(acc[m][j] + bval, 0.f);
    }
}

extern "C" void kernel_launch(void* const* d_in, const int* in_sizes, int n_in,
                              void* d_out, int out_size, void* d_ws, size_t ws_size,
                              hipStream_t stream) {
  const float* x    = (const float*)d_in[0];
  const float* wgt  = (const float*)d_in[1];
  const float* bias = (const float*)d_in[2];
  float* out = (float*)d_out;
  hipLaunchKernelGGL(lc2d_kernel, dim3(900), dim3(256), 0, stream, x, wgt, bias, out);
}